// Round 14
// baseline (361.273 us; speedup 1.0000x reference)
//
#include <hip/hip_runtime.h>
#include <hip/hip_bf16.h>
#include <stdint.h>

#define NN 10000
#define NE 250000
#define FEAT 16
#define EMB 32
#define HID 32
#define NV 12
#define EAD 9
#define NG 64

// ---------------------------------------------------------------------------
// dst in-degree histogram
// ---------------------------------------------------------------------------
__global__ void edge_stats_kernel(const int* __restrict__ dst,
                                  int* __restrict__ histD) {
    int e = blockIdx.x * blockDim.x + threadIdx.x;
    if (e >= NE) return;
    atomicAdd(&histD[dst[e]], 1);
}

// ---------------------------------------------------------------------------
// Single-block exclusive scan: histD[NN] -> rowD[NN+1], curD[NN]
// ---------------------------------------------------------------------------
__global__ __launch_bounds__(1024) void scan_kernel(const int* __restrict__ hist,
                                                    int* __restrict__ rowStart,
                                                    int* __restrict__ cursor) {
    __shared__ int part[1024];
    int t = threadIdx.x;
    int base = t * 10;
    int local[10];
    int s = 0;
#pragma unroll
    for (int i = 0; i < 10; ++i) {
        int v = (base + i < NN) ? hist[base + i] : 0;
        local[i] = s;
        s += v;
    }
    part[t] = s;
    __syncthreads();
    for (int off = 1; off < 1024; off <<= 1) {
        int v = (t >= off) ? part[t - off] : 0;
        __syncthreads();
        part[t] += v;
        __syncthreads();
    }
    int pre = (t == 0) ? 0 : part[t - 1];
#pragma unroll
    for (int i = 0; i < 10; ++i) {
        if (base + i < NN) {
            int rs = pre + local[i];
            rowStart[base + i] = rs;
            cursor[base + i] = rs;
        }
    }
    if (t == 1023) rowStart[NN] = part[1023];
}

// ---------------------------------------------------------------------------
// Permute edges to DST-sorted order (ea padded to 12 floats); record src id.
// ---------------------------------------------------------------------------
__global__ void scatter_kernel(const float* __restrict__ ea,
                               const int* __restrict__ src,
                               const int* __restrict__ dst,
                               int* __restrict__ cursorD,
                               float* __restrict__ ea_d,   // [E,12] dst-sorted
                               int* __restrict__ src_d) {  // [E]
    int e = blockIdx.x * blockDim.x + threadIdx.x;
    if (e >= NE) return;
    int dv = dst[e];
    int pos = atomicAdd(&cursorD[dv], 1);
    src_d[pos] = src[e];
#pragma unroll
    for (int j = 0; j < 12; ++j)
        ea_d[(size_t)pos * 12 + j] = (j < EAD) ? ea[(size_t)e * EAD + j] : 0.f;
}

// ---------------------------------------------------------------------------
// C-build: wave = one dst node, C accumulated in REGISTERS (no atomics).
// C[n,k,i] = sum_{e->n} hid[e,k]*h[src_e,i];  row k=32 = sbar[i] = sum h[src,i].
// Lane l: k = l&31, i-range = (l>>5)*IB .. +IB-1 (IB = DIN/2).
// Per edge: ea row broadcast (3 float4) -> hidden[k] via 9 FMA; h[src] row
// gathered from the L2-resident [N,DIN] table; IB FMAs into C regs.
// Output layout: C[n][k][i], flatK = k*DIN+i, streamed wave-coalesced.
// ---------------------------------------------------------------------------
template <int DIN>
__global__ __launch_bounds__(256) void cbuild_kernel(
    const float* __restrict__ ea_d,   // [E,12]
    const int* __restrict__ src_d,    // [E]
    const int* __restrict__ rowD,     // [N+1]
    const float* __restrict__ w1,     // [9,32]
    const float* __restrict__ b1,     // [32]
    const float* __restrict__ h,      // [N,DIN]
    float* __restrict__ C)            // [N, 33*DIN]
{
    constexpr int IB = DIN / 2;
    constexpr int K = 33 * DIN;
    int t = threadIdx.x;
    int l = t & 63;
    int n = blockIdx.x * 4 + (t >> 6);   // NN = 2500*4 exactly
    int k = l & 31;
    int ih = l >> 5;

    float w1r[EAD];
#pragma unroll
    for (int j = 0; j < EAD; ++j) w1r[j] = w1[j * 32 + k];
    float b1r = b1[k];

    float c[IB], sb[IB];
#pragma unroll
    for (int j = 0; j < IB; ++j) { c[j] = 0.f; sb[j] = 0.f; }

    int beg = rowD[n], end = rowD[n + 1];
    for (int e = beg; e < end; ++e) {
        const float4* eav = (const float4*)(ea_d + (size_t)e * 12);
        float4 a0 = eav[0], a1 = eav[1], a2 = eav[2];
        float hs = b1r;
        hs += a0.x * w1r[0] + a0.y * w1r[1] + a0.z * w1r[2] + a0.w * w1r[3];
        hs += a1.x * w1r[4] + a1.y * w1r[5] + a1.z * w1r[6] + a1.w * w1r[7];
        hs += a2.x * w1r[8];
        float hd = fmaxf(hs, 0.f);

        int sv = src_d[e];
        const float* hr = h + (size_t)sv * DIN + ih * IB;
#pragma unroll
        for (int j4 = 0; j4 < IB / 4; ++j4) {
            float4 hv = *(const float4*)(hr + j4 * 4);
            c[j4 * 4 + 0] += hd * hv.x;  sb[j4 * 4 + 0] += hv.x;
            c[j4 * 4 + 1] += hd * hv.y;  sb[j4 * 4 + 1] += hv.y;
            c[j4 * 4 + 2] += hd * hv.z;  sb[j4 * 4 + 2] += hv.z;
            c[j4 * 4 + 3] += hd * hv.w;  sb[j4 * 4 + 3] += hv.w;
        }
    }

    float* cb = C + (size_t)n * K + k * DIN + ih * IB;
#pragma unroll
    for (int j4 = 0; j4 < IB / 4; ++j4)
        *(float4*)(cb + j4 * 4) =
            make_float4(c[j4 * 4], c[j4 * 4 + 1], c[j4 * 4 + 2], c[j4 * 4 + 3]);
    if (k == 0) {   // sbar row (identical across k-lanes; one writer per ih)
        float* sbp = C + (size_t)n * K + 32 * DIN + ih * IB;
#pragma unroll
        for (int j4 = 0; j4 < IB / 4; ++j4)
            *(float4*)(sbp + j4 * 4) =
                make_float4(sb[j4 * 4], sb[j4 * 4 + 1], sb[j4 * 4 + 2], sb[j4 * 4 + 3]);
    }
}

// ---------------------------------------------------------------------------
// Fused GEMM + node update: msum[n,o] = sum_f C[n,f]*W2eq[f,o] (W2eq row f:
// k=f/DIN<32 -> w2[k, i*32+o]; k==32 -> b2[i*32+o]); then mean (deg from
// rowD), root matmul, bias, ReLU, store (+ pooling). LDS-tiled, K-tile=132.
// ---------------------------------------------------------------------------
template <int DIN, bool POOL>
__global__ __launch_bounds__(256) void gemm_node_kernel(
    const float* __restrict__ C,     // [N, 33*DIN]
    const float* __restrict__ w2,    // [32, DIN*32]
    const float* __restrict__ b2,    // [DIN*32]
    const int* __restrict__ rowD,    // [N+1]
    const float* __restrict__ hin,   // [N,DIN]
    const float* __restrict__ root,  // [DIN,32]
    const float* __restrict__ bias,  // [32]
    float* __restrict__ hout,        // [N,32]
    float* __restrict__ pooled,      // [G,32]
    const int* __restrict__ batch,
    float* __restrict__ gcnt)        // [G]
{
    constexpr int K = 33 * DIN;
    constexpr int KT = 132;
    constexpr int NT = K / KT;       // 4 (DIN=16) or 8 (DIN=32)
    __shared__ float sW[KT * 32];
    __shared__ float sC[32 * KT];
    __shared__ float sroot[DIN * 32];
    __shared__ float sh[32 * DIN];
    __shared__ int sdeg[32];

    int t = threadIdx.x;
    int o = t & 31;
    int ng = t >> 5;                  // 0..7
    int n0 = blockIdx.x * 32;

    float msum[4] = {0.f, 0.f, 0.f, 0.f};

    for (int kt = 0; kt < NT; ++kt) {
        __syncthreads();
        for (int idx = t; idx < KT * 32; idx += 256) {
            int kk = idx >> 5, o2 = idx & 31;
            int f = kt * KT + kk;
            int k = f / DIN, i = f & (DIN - 1);
            sW[idx] = (k < 32) ? w2[(size_t)k * (DIN * 32) + i * 32 + o2]
                               : b2[i * 32 + o2];
        }
        for (int idx = t; idx < 32 * KT; idx += 256) {
            int nl = idx / KT, kk = idx - nl * KT;
            int n = n0 + nl;
            sC[idx] = (n < NN) ? C[(size_t)n * K + kt * KT + kk] : 0.f;
        }
        __syncthreads();
#pragma unroll 4
        for (int kk = 0; kk < KT; ++kk) {
            float w = sW[kk * 32 + o];
#pragma unroll
            for (int q = 0; q < 4; ++q)
                msum[q] += sC[(ng * 4 + q) * KT + kk] * w;
        }
    }

    __syncthreads();
    for (int idx = t; idx < DIN * 32; idx += 256) sroot[idx] = root[idx];
    for (int idx = t; idx < 32 * DIN; idx += 256) {
        int nl = idx / DIN, i = idx - nl * DIN;
        int n = n0 + nl;
        sh[idx] = (n < NN) ? hin[(size_t)n * DIN + i] : 0.f;
    }
    if (t < 32) {
        int n = n0 + t;
        sdeg[t] = (n < NN) ? (rowD[n + 1] - rowD[n]) : 1;
    }
    __syncthreads();

    float bo = bias[o];
#pragma unroll
    for (int q = 0; q < 4; ++q) {
        int nl = ng * 4 + q;
        int n = n0 + nl;
        if (n >= NN) continue;
        float v = msum[q] / fmaxf((float)sdeg[nl], 1.f) + bo;
#pragma unroll
        for (int i = 0; i < DIN; ++i) v += sh[nl * DIN + i] * sroot[i * 32 + o];
        v = fmaxf(v, 0.f);
        hout[(size_t)n * 32 + o] = v;
        if (POOL) {
            int g = batch[n];
            atomicAdd(&pooled[g * 32 + o], v);
            if (o == 0) atomicAdd(&gcnt[g], 1.0f);
        }
    }
}

// ---------------------------------------------------------------------------
// pooled mean -> linear(32,12) -> log_softmax
// ---------------------------------------------------------------------------
__global__ void final_kernel(const float* __restrict__ pooled,
                             const float* __restrict__ gcnt,
                             const float* __restrict__ lin_w,
                             const float* __restrict__ lin_b,
                             float* __restrict__ out) {
    int g = threadIdx.x;
    if (g >= NG) return;
    float inv = 1.0f / fmaxf(gcnt[g], 1.0f);
    float p[HID];
#pragma unroll
    for (int h = 0; h < HID; ++h) p[h] = pooled[g * HID + h] * inv;
    float logits[NV];
    float mx = -1e30f;
#pragma unroll
    for (int v = 0; v < NV; ++v) {
        float s = lin_b[v];
#pragma unroll
        for (int h = 0; h < HID; ++h) s += p[h] * lin_w[h * NV + v];
        logits[v] = s;
        mx = fmaxf(mx, s);
    }
    float se = 0.f;
#pragma unroll
    for (int v = 0; v < NV; ++v) se += expf(logits[v] - mx);
    float lse = mx + logf(se);
#pragma unroll
    for (int v = 0; v < NV; ++v) out[g * NV + v] = logits[v] - lse;
}

// ---------------------------------------------------------------------------
extern "C" void kernel_launch(void* const* d_in, const int* in_sizes, int n_in,
                              void* d_out, int out_size, void* d_ws, size_t ws_size,
                              hipStream_t stream) {
    const float* x        = (const float*)d_in[0];
    const float* ea       = (const float*)d_in[1];
    const int*   eidx     = (const int*)d_in[2];
    const int*   batch    = (const int*)d_in[3];
    const float* nn1_w1   = (const float*)d_in[4];
    const float* nn1_b1   = (const float*)d_in[5];
    const float* nn1_w2   = (const float*)d_in[6];
    const float* nn1_b2   = (const float*)d_in[7];
    const float* root1    = (const float*)d_in[8];
    const float* bias1    = (const float*)d_in[9];
    const float* nn2_w1   = (const float*)d_in[10];
    const float* nn2_b1   = (const float*)d_in[11];
    const float* nn2_w2   = (const float*)d_in[12];
    const float* nn2_b2   = (const float*)d_in[13];
    const float* root2    = (const float*)d_in[14];
    const float* bias2    = (const float*)d_in[15];
    const float* lin_w    = (const float*)d_in[16];
    const float* lin_b    = (const float*)d_in[17];
    float* out = (float*)d_out;

    const int* src = eidx;
    const int* dst = eidx + NE;

    // workspace: 16B-aligned float arrays first, then ints, then the
    // contiguous zeroed region (histD, pooled, gcnt).
    char* base = (char*)d_ws;
    float* Cbuf   = (float*)base;                           // NN*1056
    float* ea_d   = Cbuf + (size_t)NN * 1056;               // NE*12
    float* h1     = ea_d + (size_t)NE * 12;                 // NN*32
    float* h2     = h1 + (size_t)NN * 32;                   // NN*32
    int*   src_d  = (int*)(h2 + (size_t)NN * 32);           // NE
    int*   rowD   = src_d + NE;                             // NN+1
    int*   curD   = rowD + NN + 1;                          // NN
    int*   histD  = curD + NN;                              // NN (zeroed from here)
    float* pooled = (float*)(histD + NN);                   // NG*32
    float* gcnt   = pooled + NG * 32;                       // NG
    size_t zero_bytes = ((size_t)NN + NG * 32 + NG) * 4;

    hipMemsetAsync(histD, 0, zero_bytes, stream);

    // ---- dst-sort pre-pass (shared by both convs) ----
    edge_stats_kernel<<<(NE + 255) / 256, 256, 0, stream>>>(dst, histD);
    scan_kernel<<<1, 1024, 0, stream>>>(histD, rowD, curD);
    scatter_kernel<<<(NE + 255) / 256, 256, 0, stream>>>(ea, src, dst, curD,
                                                         ea_d, src_d);

    const int cb_grid = NN / 4;             // 2500, wave per node
    const int gn_grid = (NN + 31) / 32;     // 313

    // ---- conv1 ----
    cbuild_kernel<FEAT><<<cb_grid, 256, 0, stream>>>(
        ea_d, src_d, rowD, nn1_w1, nn1_b1, x, Cbuf);
    gemm_node_kernel<FEAT, false><<<gn_grid, 256, 0, stream>>>(
        Cbuf, nn1_w2, nn1_b2, rowD, x, root1, bias1, h1,
        nullptr, nullptr, nullptr);

    // ---- conv2 ----
    cbuild_kernel<EMB><<<cb_grid, 256, 0, stream>>>(
        ea_d, src_d, rowD, nn2_w1, nn2_b1, h1, Cbuf);
    gemm_node_kernel<EMB, true><<<gn_grid, 256, 0, stream>>>(
        Cbuf, nn2_w2, nn2_b2, rowD, h1, root2, bias2, h2,
        pooled, batch, gcnt);

    // ---- head ----
    final_kernel<<<1, 64, 0, stream>>>(pooled, gcnt, lin_w, lin_b, out);
}